// Round 11
// baseline (708.239 us; speedup 1.0000x reference)
//
#include <hip/hip_runtime.h>
#include <math.h>

constexpr int DH = 256;
#define EPSV 1e-5f

typedef __bf16 bf16_t;
typedef bf16_t bf16x8 __attribute__((ext_vector_type(8)));
typedef float floatx4 __attribute__((ext_vector_type(4)));

// fast gelu: tanh via hardware exp (v_exp_f32)
__device__ __forceinline__ float gelu_f(float x) {
    float x3 = x * x * x;
    float z = 0.7978845608028654f * (x + 0.044715f * x3);
    float e = __expf(2.0f * z);
    float t = 1.0f - 2.0f / (e + 1.0f);
    return 0.5f * x * (1.0f + t);
}

__device__ __forceinline__ unsigned short f2bf(float x) {
    unsigned int u = __float_as_uint(x);
    u += 0x7FFFu + ((u >> 16) & 1u);
    return (unsigned short)(u >> 16);
}

__device__ __forceinline__ float bf2f(unsigned short u) {
    return __uint_as_float(((unsigned int)u) << 16);
}

__device__ __forceinline__ void addbf8(float* acc, uint4 u) {
    const unsigned short* p = (const unsigned short*)&u;
#pragma unroll
    for (int k = 0; k < 8; k++) acc[k] += bf2f(p[k]);
}

__device__ __forceinline__ void addbf4(float* acc, ushort4 u) {
    acc[0] += bf2f(u.x);
    acc[1] += bf2f(u.y);
    acc[2] += bf2f(u.z);
    acc[3] += bf2f(u.w);
}

// ---------------- padded-adjacency build (count-free CSR replacement) ----------------
// scatter directly into padded adjacency esrc_pad[node][64]; atomicAdd's return value
// is the slot, and cursor[d] after the kernel IS the degree (r10: -52us vs count+scan).

__global__ void scatter_pad_k(const int* __restrict__ src, const int* __restrict__ dst,
                              int* __restrict__ cursor, int* __restrict__ esrc_pad,
                              int e, int n) {
    int base = ((int)blockIdx.x * 256 + (int)threadIdx.x) * 8;
    int m = e - base; if (m > 8) m = 8;
    if (m <= 0) return;
    int dd[8], sv[8], pos[8];
#pragma unroll
    for (int k = 0; k < 8; k++)
        if (k < m) {
            int d = dst[base + k];
            dd[k] = (d < 0) ? 0 : ((d >= n) ? n - 1 : d);
            int s = src[base + k];
            sv[k] = (s < 0) ? 0 : ((s >= n) ? n - 1 : s);
        }
#pragma unroll
    for (int k = 0; k < 8; k++)
        if (k < m) pos[k] = atomicAdd(&cursor[dd[k]], 1);
#pragma unroll
    for (int k = 0; k < 8; k++)
        if (k < m && pos[k] < 64) esrc_pad[(dd[k] << 6) + pos[k]] = sv[k];
}

// ---------------- deg + weights transpose + xsc conversion, one launch ------------

__global__ void prep_k(const int* __restrict__ cnt, float* __restrict__ isd,
                       float* __restrict__ sdeg, int n, int gN,
                       const float* __restrict__ s0, const float* __restrict__ s1,
                       const float* __restrict__ s2, const float* __restrict__ s3,
                       const float* __restrict__ s4, const float* __restrict__ s5,
                       unsigned short* __restrict__ d0, unsigned short* __restrict__ d1,
                       unsigned short* __restrict__ d2, unsigned short* __restrict__ d3,
                       unsigned short* __restrict__ d4, unsigned short* __restrict__ d5,
                       const float* __restrict__ x, unsigned short* __restrict__ xsc,
                       int n4) {
    int b = blockIdx.x;
    if (b < gN) {
        int i = b * 256 + threadIdx.x;
        if (i < n) {
            float d = (float)cnt[i] + 1.0f;   // +1 self loop
            float r = rsqrtf(d);
            isd[i] = r;
            sdeg[i] = d * r;
        }
        return;
    }
    int b2 = b - gN;
    if (b2 < 1536) {
        int y = b2 >> 8, k = b2 & 255, nn = threadIdx.x;
        const float* S;
        unsigned short* D;
        int K;
        switch (y) {
            case 0: S = s0; D = d0; K = 128; break;
            case 1: S = s1; D = d1; K = 128; break;
            case 2: S = s2; D = d2; K = 256; break;
            case 3: S = s3; D = d3; K = 256; break;
            case 4: S = s4; D = d4; K = 256; break;
            default: S = s5; D = d5; K = 256; break;
        }
        if (k >= K) return;
        D[(size_t)nn * K + k] = f2bf(S[(size_t)k * 256 + nn]);
    } else {
        int i4 = (b2 - 1536) * 256 + threadIdx.x;
        if (i4 < n4) {
            float si = rsqrtf((float)cnt[i4 >> 5] + 1.0f);
            float4 v = ((const float4*)x)[i4];
            ushort4 o;
            o.x = f2bf(si * v.x); o.y = f2bf(si * v.y);
            o.z = f2bf(si * v.z); o.w = f2bf(si * v.w);
            ((ushort4*)xsc)[i4] = o;
        }
    }
}

// ---------------- bf16 MFMA GEMM: full-width 512-thread blocks, B in VGPRs ------------
// (unchanged from r10 — see prior rounds for flag semantics)

template <int K, bool BIAS, bool GELU_, bool SPRE, bool SCALE, bool STATS, bool HEAD,
          bool PF, bool FUSEA, bool WRITEH, bool BNIN>
__global__ __launch_bounds__(512) void gemm_bf_k(const unsigned short* __restrict__ A,
                                                 const unsigned short* __restrict__ Wt,
                                                 const float* __restrict__ bias,
                                                 const float* __restrict__ rowscale,
                                                 unsigned short* __restrict__ CB,
                                                 int M,
                                                 const float* __restrict__ hw,
                                                 const float* __restrict__ hb,
                                                 float* __restrict__ hout,
                                                 float* __restrict__ bnp_out,
                                                 const unsigned short* __restrict__ resid,
                                                 unsigned short* __restrict__ hwr,
                                                 const float* __restrict__ bnp_in,
                                                 const float* __restrict__ bn_g,
                                                 const float* __restrict__ bn_b,
                                                 float inv_n) {
    constexpr int CH = K / 32;
    const int lane = threadIdx.x & 63;
    const int wave = threadIdx.x >> 6;
    const int wm = wave & 1;               // row group (16 rows)
    const int wn = wave >> 1;              // col quarter
    const int l15 = lane & 15;
    const int quad = lane >> 4;

    __shared__ unsigned short al[FUSEA ? 2 * 32 * 256 : 1];
    __shared__ float hsum4[HEAD ? 128 : 1];
    __shared__ float st[STATS ? 1024 : 1];
    __shared__ float ssl[(FUSEA || BNIN) ? 512 : 1];   // [0..255]=scale, [256..511]=shift

    if constexpr (BNIN) {
        int t = threadIdx.x;
        if (t < 256) {
            float S = 0.f, S2 = 0.f;
#pragma unroll 8
            for (int r = 0; r < 64; r++) {
                S += bnp_in[r * 512 + t];
                S2 += bnp_in[r * 512 + 256 + t];
            }
            float mu = S * inv_n;
            float var = S2 * inv_n - mu * mu;
            float sc = bn_g[t] * rsqrtf(var + EPSV);
            ssl[t] = sc;
            ssl[256 + t] = bn_b[t] - mu * sc;
        }
        __syncthreads();
    }

    bf16x8 bfr[CH][4];
#pragma unroll
    for (int c = 0; c < CH; c++)
#pragma unroll
        for (int j = 0; j < 4; j++) {
            int col = wn * 64 + j * 16 + l15;
            bfr[c][j] = *(const bf16x8*)&Wt[(size_t)col * K + c * 32 + quad * 8];
        }

    float hwv[16];
    if (HEAD) {
#pragma unroll
        for (int j = 0; j < 4; j++) {
            float4 w4 = *(const float4*)&hw[wn * 64 + j * 16 + quad * 4];
            hwv[j * 4 + 0] = w4.x; hwv[j * 4 + 1] = w4.y;
            hwv[j * 4 + 2] = w4.z; hwv[j * 4 + 3] = w4.w;
        }
    }
    float sacc[STATS ? 16 : 1], s2acc[STATS ? 16 : 1];
    if (STATS) {
#pragma unroll
        for (int k = 0; k < 16; k++) { sacc[k] = 0.f; s2acc[k] = 0.f; }
    }

    const int nTiles = (M + 31) >> 5;
    const int gstride = gridDim.x;

    // FUSEA thread mapping for the transform stage
    const int tr = threadIdx.x >> 4;            // local row 0..31
    const int tc = (threadIdx.x & 15) * 16;     // col base (16 cols/thread)
    const int sw = (tr & 7) << 3;               // LDS slot swizzle (ushort units)
    const int rr = wm * 16 + l15;               // fragment row
    const int rsw = (rr & 7) << 3;

    bf16x8 a[CH];
    uint4 g0, g1, r0, r1;
    if (FUSEA) {
        int rt0 = blockIdx.x;
        if (rt0 < nTiles) {
            int grow = rt0 * 32 + tr;
            int gc = (grow < M) ? grow : (M - 1);
            const unsigned short* gp = &A[(size_t)gc * 256 + tc];
            const unsigned short* rp = &resid[(size_t)gc * 256 + tc];
            g0 = *(const uint4*)gp; g1 = *(const uint4*)(gp + 8);
            r0 = *(const uint4*)rp; r1 = *(const uint4*)(rp + 8);
        }
    } else if (PF) {
        int rt0 = blockIdx.x;
        if (rt0 < nTiles) {
            int g = rt0 * 32 + wm * 16 + l15;
            int gc = (g < M) ? g : (M - 1);
            const unsigned short* ap = &A[(size_t)gc * K + quad * 8];
#pragma unroll
            for (int c = 0; c < CH; c++) a[c] = *(const bf16x8*)(ap + c * 32);
        }
    }

    int p = 0;
    for (int rt = blockIdx.x; rt < nTiles; rt += gstride) {
        int gr = rt * 32 + wm * 16 + l15;

        if constexpr (FUSEA) {
            // transform current raw tile -> bf16, LDS (+ optional h store)
            int grow = rt * 32 + tr;
            float4 sa = *(const float4*)&ssl[tc];
            float4 sb = *(const float4*)&ssl[tc + 4];
            float4 sc = *(const float4*)&ssl[tc + 8];
            float4 sd = *(const float4*)&ssl[tc + 12];
            float4 ha = *(const float4*)&ssl[256 + tc];
            float4 hbv = *(const float4*)&ssl[256 + tc + 4];
            float4 hc = *(const float4*)&ssl[256 + tc + 8];
            float4 hd = *(const float4*)&ssl[256 + tc + 12];
            float scv[16] = {sa.x, sa.y, sa.z, sa.w, sb.x, sb.y, sb.z, sb.w,
                             sc.x, sc.y, sc.z, sc.w, sd.x, sd.y, sd.z, sd.w};
            float shv[16] = {ha.x, ha.y, ha.z, ha.w, hbv.x, hbv.y, hbv.z, hbv.w,
                             hc.x, hc.y, hc.z, hc.w, hd.x, hd.y, hd.z, hd.w};
            unsigned short gbuf[16], rbuf[16];
            *(uint4*)&gbuf[0] = g0; *(uint4*)&gbuf[8] = g1;
            *(uint4*)&rbuf[0] = r0; *(uint4*)&rbuf[8] = r1;
            unsigned short hv[16];
#pragma unroll
            for (int k = 0; k < 16; k++) {
                float v = bf2f(gbuf[k]) * scv[k] + shv[k];
                hv[k] = f2bf(gelu_f(v) + bf2f(rbuf[k]));
            }
            *(uint4*)&al[p * 8192 + tr * 256 + (tc ^ sw)] = *(const uint4*)&hv[0];
            *(uint4*)&al[p * 8192 + tr * 256 + ((tc + 8) ^ sw)] = *(const uint4*)&hv[8];
            if (WRITEH && grow < M) {
                *(uint4*)&hwr[(size_t)grow * 256 + tc] = *(const uint4*)&hv[0];
                *(uint4*)&hwr[(size_t)grow * 256 + tc + 8] = *(const uint4*)&hv[8];
            }
            // prefetch next raw tile (lands during MFMA of this tile)
            int rtn = rt + gstride;
            if (rtn < nTiles) {
                int gn = rtn * 32 + tr;
                int gc2 = (gn < M) ? gn : (M - 1);
                const unsigned short* gp = &A[(size_t)gc2 * 256 + tc];
                const unsigned short* rp = &resid[(size_t)gc2 * 256 + tc];
                g0 = *(const uint4*)gp; g1 = *(const uint4*)(gp + 8);
                r0 = *(const uint4*)rp; r1 = *(const uint4*)(rp + 8);
            }
            __syncthreads();
#pragma unroll
            for (int c = 0; c < CH; c++)
                a[c] = *(const bf16x8*)&al[p * 8192 + rr * 256 + ((c * 32 + quad * 8) ^ rsw)];
        } else if constexpr (!PF) {
            int grc = (gr < M) ? gr : (M - 1);
            const unsigned short* ap = &A[(size_t)grc * K + quad * 8];
#pragma unroll
            for (int c = 0; c < CH; c++) a[c] = *(const bf16x8*)(ap + c * 32);
        }

        bf16x8 an[CH];
        if (PF && !FUSEA) {
            int rtn = rt + gstride;
            if (rtn < nTiles) {
                int gn = rtn * 32 + wm * 16 + l15;
                int gcn = (gn < M) ? gn : (M - 1);
                const unsigned short* apn = &A[(size_t)gcn * K + quad * 8];
#pragma unroll
                for (int c = 0; c < CH; c++) an[c] = *(const bf16x8*)(apn + c * 32);
            }
        }

        floatx4 acc[4];
#pragma unroll
        for (int j = 0; j < 4; j++) acc[j] = (floatx4){0.f, 0.f, 0.f, 0.f};
#pragma unroll
        for (int c = 0; c < CH; c++)
#pragma unroll
            for (int j = 0; j < 4; j++)
                acc[j] = __builtin_amdgcn_mfma_f32_16x16x32_bf16(bfr[c][j], a[c], acc[j], 0, 0, 0);

        float hpart = 0.f;
        if (gr < M) {
            float rs = (SPRE || SCALE) ? rowscale[gr] : 1.0f;
#pragma unroll
            for (int j = 0; j < 4; j++) {
                int gc0 = wn * 64 + j * 16 + quad * 4;       // 4 consecutive C-cols
                float4 bv;
                if (BIAS) bv = *(const float4*)&bias[gc0];
                float v0 = acc[j][0], v1 = acc[j][1], v2 = acc[j][2], v3 = acc[j][3];
                if (SPRE) { v0 *= rs; v1 *= rs; v2 *= rs; v3 *= rs; }
                if (BIAS) { v0 += bv.x; v1 += bv.y; v2 += bv.z; v3 += bv.w; }
                if (GELU_) { v0 = gelu_f(v0); v1 = gelu_f(v1); v2 = gelu_f(v2); v3 = gelu_f(v3); }
                if (SCALE) { v0 *= rs; v1 *= rs; v2 *= rs; v3 *= rs; }
                if (STATS) {
                    sacc[j * 4 + 0] += v0; s2acc[j * 4 + 0] += v0 * v0;
                    sacc[j * 4 + 1] += v1; s2acc[j * 4 + 1] += v1 * v1;
                    sacc[j * 4 + 2] += v2; s2acc[j * 4 + 2] += v2 * v2;
                    sacc[j * 4 + 3] += v3; s2acc[j * 4 + 3] += v3 * v3;
                }
                if (HEAD) {
                    hpart += v0 * hwv[j * 4 + 0] + v1 * hwv[j * 4 + 1]
                           + v2 * hwv[j * 4 + 2] + v3 * hwv[j * 4 + 3];
                } else {
                    ushort4 o;
                    o.x = f2bf(v0); o.y = f2bf(v1); o.z = f2bf(v2); o.w = f2bf(v3);
                    *(ushort4*)&CB[(size_t)gr * DH + gc0] = o;
                }
            }
        }
        if constexpr (HEAD) {
            hpart += __shfl_xor(hpart, 16, 64);
            hpart += __shfl_xor(hpart, 32, 64);
            if (quad == 0) hsum4[wn * 32 + wm * 16 + l15] = hpart;
            __syncthreads();
            if (threadIdx.x < 32) {
                int grow = rt * 32 + (int)threadIdx.x;
                if (grow < M)
                    hout[grow] = hsum4[threadIdx.x] + hsum4[32 + threadIdx.x] +
                                 hsum4[64 + threadIdx.x] + hsum4[96 + threadIdx.x] + hb[0];
            }
            __syncthreads();
        }

        if constexpr (FUSEA) {
            p ^= 1;
        } else if (PF) {
#pragma unroll
            for (int c = 0; c < CH; c++) a[c] = an[c];
        }
    }

    if (STATS) {
#pragma unroll
        for (int m = 1; m < 16; m <<= 1) {
#pragma unroll
            for (int k = 0; k < 16; k++) {
                sacc[k] += __shfl_xor(sacc[k], m, 64);
                s2acc[k] += __shfl_xor(s2acc[k], m, 64);
            }
        }
        if (l15 == 0) {
#pragma unroll
            for (int j = 0; j < 4; j++)
#pragma unroll
                for (int k = 0; k < 4; k++) {
                    int col = wn * 64 + j * 16 + quad * 4 + k;
                    st[wm * 512 + col] = sacc[j * 4 + k];
                    st[wm * 512 + 256 + col] = s2acc[j * 4 + k];
                }
        }
        __syncthreads();
        int t = threadIdx.x;
        atomicAdd(&bnp_out[(size_t)(blockIdx.x & 63) * 512 + t], st[t] + st[512 + t]);
    }
}

// ------------- merged: proj GEMM (blocks [0,nProjB)) + layer-0 aggregation ------------

__global__ __launch_bounds__(512, 4) void aggx_proj_k(
        const unsigned short* __restrict__ xsc,
        const int* __restrict__ esrc_pad,
        const int* __restrict__ cnt,
        const float* __restrict__ isd,
        unsigned short* __restrict__ axs,
        int n, int nProjB,
        const unsigned short* __restrict__ pjt,
        const float* __restrict__ pjb,
        const float* __restrict__ sdeg,
        unsigned short* __restrict__ pjo) {
    if ((int)blockIdx.x < nProjB) {
        const int lane = threadIdx.x & 63;
        const int wave = threadIdx.x >> 6;
        const int wm = wave & 1;
        const int wn = wave >> 1;
        const int l15 = lane & 15;
        const int quad = lane >> 4;
        bf16x8 bfr[4][4];
#pragma unroll
        for (int c = 0; c < 4; c++)
#pragma unroll
            for (int j = 0; j < 4; j++) {
                int col = wn * 64 + j * 16 + l15;
                bfr[c][j] = *(const bf16x8*)&pjt[(size_t)col * 128 + c * 32 + quad * 8];
            }
        const int nTiles = (n + 31) >> 5;
        for (int rt = blockIdx.x; rt < nTiles; rt += nProjB) {
            int gr = rt * 32 + wm * 16 + l15;
            int grc = (gr < n) ? gr : (n - 1);
            const unsigned short* ap = &xsc[(size_t)grc * 128 + quad * 8];
            bf16x8 a[4];
#pragma unroll
            for (int c = 0; c < 4; c++) a[c] = *(const bf16x8*)(ap + c * 32);
            floatx4 acc[4];
#pragma unroll
            for (int j = 0; j < 4; j++) acc[j] = (floatx4){0.f, 0.f, 0.f, 0.f};
#pragma unroll
            for (int c = 0; c < 4; c++)
#pragma unroll
                for (int j = 0; j < 4; j++)
                    acc[j] = __builtin_amdgcn_mfma_f32_16x16x32_bf16(bfr[c][j], a[c], acc[j], 0, 0, 0);
            if (gr < n) {
                float rs = sdeg[gr];
#pragma unroll
                for (int j = 0; j < 4; j++) {
                    int gc0 = wn * 64 + j * 16 + quad * 4;
                    float4 bv = *(const float4*)&pjb[gc0];
                    ushort4 o;
                    o.x = f2bf(acc[j][0] * rs + bv.x);
                    o.y = f2bf(acc[j][1] * rs + bv.y);
                    o.z = f2bf(acc[j][2] * rs + bv.z);
                    o.w = f2bf(acc[j][3] * rs + bv.w);
                    *(ushort4*)&pjo[(size_t)gr * DH + gc0] = o;
                }
            }
        }
        return;
    }
    // ---- layer-0 aggregation: 16 rows per 512-thread block, padded adjacency ----
    int b = blockIdx.x - nProjB;
    int half = threadIdx.x >> 5;      // 0..15
    int sub = threadIdx.x & 31;
    int i = b * 16 + half;
    if (i >= n) return;
    int len = cnt[i]; if (len > 64) len = 64;
    const int* row = &esrc_pad[i << 6];
    int c = sub * 4;
    float acc[4] = {0.f, 0.f, 0.f, 0.f};
    addbf4(acc, *(const ushort4*)&xsc[(size_t)i * 128 + c]);   // self
    int e = 0;
    for (; e + 7 < len; e += 8) {
        int s[8];
        ushort4 u[8];
#pragma unroll
        for (int k = 0; k < 8; k++) s[k] = row[e + k];
#pragma unroll
        for (int k = 0; k < 8; k++) u[k] = *(const ushort4*)&xsc[(size_t)s[k] * 128 + c];
#pragma unroll
        for (int k = 0; k < 8; k++) addbf4(acc, u[k]);
    }
    for (; e + 1 < len; e += 2) {
        int s0 = row[e], s1 = row[e + 1];
        ushort4 a = *(const ushort4*)&xsc[(size_t)s0 * 128 + c];
        ushort4 bb = *(const ushort4*)&xsc[(size_t)s1 * 128 + c];
        addbf4(acc, a);
        addbf4(acc, bb);
    }
    if (e < len)
        addbf4(acc, *(const ushort4*)&xsc[(size_t)row[e] * 128 + c]);
    float si = isd[i];
    ushort4 o;
    o.x = f2bf(si * acc[0]); o.y = f2bf(si * acc[1]);
    o.z = f2bf(si * acc[2]); o.w = f2bf(si * acc[3]);
    *(ushort4*)&axs[(size_t)i * 128 + c] = o;
}

// ---------------- layers 1,2 aggregation: XCD column-sliced + BN partials ----------
// slice = blockIdx & 7: default dispatch round-robins blocks across the 8 XCDs, so all
// blocks of a slice share one XCD whose gather working set is a 32-col slice of hws =
// 50000 x 64B = 3.2MB < 4MB L2. Gathers become L2 HITS instead of L3/HBM misses.
// Wave layout: one wave per row: 64 lanes = 16 edge-slots x 4 col-chunks(8 cols);
// shfl_xor(4..32) reduces over edge-slots; no degree divergence within the wave.
// BN partials: per-wave register accumulation, 64 end-of-kernel atomics per wave.
// If the blockIdx->XCD mapping differs, correctness is unaffected (perf heuristic only).

__global__ __launch_bounds__(256) void agg_h_s_k(const unsigned short* __restrict__ hws,
                                                 const int* __restrict__ esrc_pad,
                                                 const int* __restrict__ cnt,
                                                 const float* __restrict__ isd,
                                                 const float* __restrict__ bias,
                                                 unsigned short* __restrict__ out,
                                                 float* __restrict__ bnp, int n) {
    const int slice = blockIdx.x & 7;
    const int wid = threadIdx.x >> 6;
    const int lane = threadIdx.x & 63;
    const int es = lane >> 2;              // edge slot 0..15
    const int ch = lane & 3;               // col chunk 0..3
    const int colb = slice * 32 + ch * 8;  // this lane's 8 columns
    const int rowStride = (gridDim.x >> 3) * 4;
    const int row0 = ((int)(blockIdx.x >> 3)) * 4 + wid;

    float bv[8];
#pragma unroll
    for (int k = 0; k < 8; k++) bv[k] = bias[colb + k];
    float bns[8] = {0.f, 0.f, 0.f, 0.f, 0.f, 0.f, 0.f, 0.f};
    float bns2[8] = {0.f, 0.f, 0.f, 0.f, 0.f, 0.f, 0.f, 0.f};

    for (int i = row0; i < n; i += rowStride) {
        int len = cnt[i]; if (len > 64) len = 64;
        const int* rowp = &esrc_pad[i << 6];
        float acc[8] = {0.f, 0.f, 0.f, 0.f, 0.f, 0.f, 0.f, 0.f};
        if (es == 0)
            addbf8(acc, *(const uint4*)&hws[(size_t)i * DH + colb]);   // self
        for (int e = 0; e < len; e += 16) {
            int slot = e + es;
            if (slot < len) {
                int s = rowp[slot];
                addbf8(acc, *(const uint4*)&hws[(size_t)s * DH + colb]);
            }
        }
        // reduce over the 16 edge slots (lanes at stride 4, bits 2..5 of lane)
#pragma unroll
        for (int off = 4; off <= 32; off <<= 1)
#pragma unroll
            for (int k = 0; k < 8; k++) acc[k] += __shfl_xor(acc[k], off, 64);
        if (es == 0) {
            float si = isd[i];
            unsigned short ob[8];
#pragma unroll
            for (int k = 0; k < 8; k++) {
                float o = si * acc[k] + bv[k];
                ob[k] = f2bf(o);
                bns[k] += o;
                bns2[k] += o * o;
            }
            *(uint4*)&out[(size_t)i * DH + colb] = *(const uint4*)ob;
        }
    }
    if (es == 0) {
        size_t rowb = (size_t)(blockIdx.x & 63) * 512;
#pragma unroll
        for (int k = 0; k < 8; k++) {
            atomicAdd(&bnp[rowb + colb + k], bns[k]);
            atomicAdd(&bnp[rowb + 256 + colb + k], bns2[k]);
        }
    }
}

// ---------------- launch ----------------

extern "C" void kernel_launch(void* const* d_in, const int* in_sizes, int n_in,
                              void* d_out, int out_size, void* d_ws, size_t ws_size,
                              hipStream_t stream) {
    const float* x = (const float*)d_in[0];
    const int* eidx = (const int*)d_in[1];       // int64 in ref -> int32 on device
    const float* conv_w0 = (const float*)d_in[3];
    const float* conv_b0 = (const float*)d_in[4];
    const float* conv_w1 = (const float*)d_in[5];
    const float* conv_b1 = (const float*)d_in[6];
    const float* conv_w2 = (const float*)d_in[7];
    const float* conv_b2 = (const float*)d_in[8];
    const float* bn_g0 = (const float*)d_in[9];
    const float* bn_b0 = (const float*)d_in[10];
    const float* bn_g1 = (const float*)d_in[11];
    const float* bn_b1 = (const float*)d_in[12];
    const float* bn_g2 = (const float*)d_in[13];
    const float* bn_b2 = (const float*)d_in[14];
    const float* proj_w = (const float*)d_in[15];
    const float* proj_b = (const float*)d_in[16];
    const float* lin_w0 = (const float*)d_in[17];
    const float* lin_b0 = (const float*)d_in[18];
    const float* lin_w1 = (const float*)d_in[19];
    const float* lin_b1 = (const float*)d_in[20];
    const float* head_w = (const float*)d_in[21];
    const float* head_b = (const float*)d_in[22];

    const int N = in_sizes[2];
    const int E = in_sizes[1] / 2;
    const int* esrc_in = eidx;
    const int* edst_in = eidx + E;

    char* ws = (char*)d_ws;
    auto alloc = [&](size_t b) -> char* {
        char* p = ws;
        ws += (b + 255) & ~(size_t)255;
        return p;
    };
    unsigned short* h1_bf = (unsigned short*)alloc((size_t)N * DH * 2);
    unsigned short* h2_bf = (unsigned short*)alloc((size_t)N * DH * 2);
    unsigned short* hw_bf = (unsigned short*)alloc((size_t)N * DH * 2);
    unsigned short* pj_bf = (unsigned short*)alloc((size_t)N * DH * 2);
    unsigned short* gcn_bf = (unsigned short*)alloc((size_t)N * DH * 2);
    unsigned short* xsc = (unsigned short*)alloc((size_t)N * 128 * 2);
    unsigned short* axs = (unsigned short*)alloc((size_t)N * 128 * 2);
    unsigned short* w0t = (unsigned short*)alloc((size_t)256 * 128 * 2);
    unsigned short* pjt = (unsigned short*)alloc((size_t)256 * 128 * 2);
    unsigned short* w1t = (unsigned short*)alloc((size_t)256 * 256 * 2);
    unsigned short* w2t = (unsigned short*)alloc((size_t)256 * 256 * 2);
    unsigned short* l0t = (unsigned short*)alloc((size_t)256 * 256 * 2);
    unsigned short* l1t = (unsigned short*)alloc((size_t)256 * 256 * 2);
    // ---- zeroed region: 3 BN partial buffers + cursor (ONE memset) ----
    float* bnp0 = (float*)alloc((size_t)64 * 512 * 4);
    float* bnp1 = (float*)alloc((size_t)64 * 512 * 4);
    float* bnp2 = (float*)alloc((size_t)64 * 512 * 4);
    int* cursor = (int*)alloc((size_t)N * 4);       // slot counter -> degree
    const size_t zbytes = 3 * (size_t)64 * 512 * 4 + (size_t)N * 4;
    // ---- end zeroed region ----
    int* esrc_pad = (int*)alloc((size_t)N * 64 * 4);
    float* isd = (float*)alloc((size_t)N * 4);
    float* sdeg = (float*)alloc((size_t)N * 4);

    const int gE8 = (E + 2047) / 2048;           // 8 edges/thread scatter blocks
    const int gAgg16 = (N + 15) / 16;
    const int gN = (N + 255) / 256;
    const int gGemm = 256;                       // persistent full-width blocks (1/CU)
    const int gSlice = 2048;                     // 8 blocks/CU; slice = blockIdx & 7
    const int n4 = N * 128 / 4;
    const int gPrep = gN + 1536 + (n4 + 255) / 256;
    const float inv_n = 1.0f / (float)N;

    hipMemsetAsync(bnp0, 0, zbytes, stream);
    // count-free CSR: scatter directly into padded adjacency (atomic slot = degree)
    scatter_pad_k<<<gE8, 256, 0, stream>>>(esrc_in, edst_in, cursor, esrc_pad, E, N);
    // deg (from cursor) + weight transposes + xsc, one launch
    prep_k<<<gPrep, 256, 0, stream>>>(cursor, isd, sdeg, N, gN,
                                      conv_w0, proj_w, conv_w1, conv_w2, lin_w0, lin_w1,
                                      w0t, pjt, w1t, w2t, l0t, l1t, x, xsc, n4);

    // ---- layer 0: proj GEMM + aggregation merged ----
    aggx_proj_k<<<256 + gAgg16, 512, 0, stream>>>(xsc, esrc_pad, cursor, isd, axs, N,
                                                  256, pjt, proj_b, sdeg, pj_bf);
    // conv0 GEMM, BN stats -> bnp0 (atomic accumulate)
    gemm_bf_k<128, true, false, false, false, true, false, true, false, false, false>
        <<<gGemm, 512, 0, stream>>>(axs, w0t, conv_b0, nullptr, gcn_bf, N,
                                    nullptr, nullptr, nullptr, bnp0, nullptr, nullptr,
                                    nullptr, nullptr, nullptr, 0.f);

    // ---- layer 1: BNIN(bnp0) + fused BN+gelu+residual A-stage; sliced agg -> bnp1 ----
    gemm_bf_k<256, false, false, false, true, false, false, false, true, true, true>
        <<<gGemm, 512, 0, stream>>>(gcn_bf, w1t, nullptr, isd, hw_bf, N,
                                    nullptr, nullptr, nullptr, nullptr, pj_bf, h1_bf,
                                    bnp0, bn_g0, bn_b0, inv_n);
    agg_h_s_k<<<gSlice, 256, 0, stream>>>(hw_bf, esrc_pad, cursor, isd, conv_b1,
                                          gcn_bf, bnp1, N);

    // ---- layer 2: BNIN(bnp1) + fused A-stage; sliced agg -> bnp2 ----
    gemm_bf_k<256, false, false, false, true, false, false, false, true, true, true>
        <<<gGemm, 512, 0, stream>>>(gcn_bf, w2t, nullptr, isd, hw_bf, N,
                                    nullptr, nullptr, nullptr, nullptr, h1_bf, h2_bf,
                                    bnp1, bn_g1, bn_b1, inv_n);
    agg_h_s_k<<<gSlice, 256, 0, stream>>>(hw_bf, esrc_pad, cursor, isd, conv_b2,
                                          gcn_bf, bnp2, N);

    // ---- MLP: lin0 with BNIN(bnp2) + fused h3 A-stage (h3 not materialized) ----
    gemm_bf_k<256, true, true, false, false, false, false, false, true, false, true>
        <<<gGemm, 512, 0, stream>>>(gcn_bf, l0t, lin_b0, nullptr, h1_bf, N,
                                    nullptr, nullptr, nullptr, nullptr, h2_bf, nullptr,
                                    bnp2, bn_g2, bn_b2, inv_n);
    // lin1 + head fused (LDS combine, non-atomic store -> no d_out memset)
    gemm_bf_k<256, true, true, false, false, false, true, false, false, false, false>
        <<<gGemm, 512, 0, stream>>>(h1_bf, l1t, lin_b1, nullptr, nullptr, N,
                                    head_w, head_b, (float*)d_out, nullptr, nullptr, nullptr,
                                    nullptr, nullptr, nullptr, 0.f);
}

// Round 12
// 501.417 us; speedup vs baseline: 1.4125x; 1.4125x over previous
//
#include <hip/hip_runtime.h>
#include <math.h>

constexpr int DH = 256;
#define EPSV 1e-5f

typedef __bf16 bf16_t;
typedef bf16_t bf16x8 __attribute__((ext_vector_type(8)));
typedef float floatx4 __attribute__((ext_vector_type(4)));

// fast gelu: tanh via hardware exp (v_exp_f32)
__device__ __forceinline__ float gelu_f(float x) {
    float x3 = x * x * x;
    float z = 0.7978845608028654f * (x + 0.044715f * x3);
    float e = __expf(2.0f * z);
    float t = 1.0f - 2.0f / (e + 1.0f);
    return 0.5f * x * (1.0f + t);
}

__device__ __forceinline__ unsigned short f2bf(float x) {
    unsigned int u = __float_as_uint(x);
    u += 0x7FFFu + ((u >> 16) & 1u);
    return (unsigned short)(u >> 16);
}

__device__ __forceinline__ float bf2f(unsigned short u) {
    return __uint_as_float(((unsigned int)u) << 16);
}

__device__ __forceinline__ void addbf8(float* acc, uint4 u) {
    const unsigned short* p = (const unsigned short*)&u;
#pragma unroll
    for (int k = 0; k < 8; k++) acc[k] += bf2f(p[k]);
}

__device__ __forceinline__ void addbf4(float* acc, ushort4 u) {
    acc[0] += bf2f(u.x);
    acc[1] += bf2f(u.y);
    acc[2] += bf2f(u.z);
    acc[3] += bf2f(u.w);
}

// ---------------- padded-adjacency build (count-free CSR replacement) ----------------
// scatter directly into padded adjacency esrc_pad[node][64]; atomicAdd's return value
// is the slot, and cursor[d] after the kernel IS the degree (r10: -52us vs count+scan).

__global__ void scatter_pad_k(const int* __restrict__ src, const int* __restrict__ dst,
                              int* __restrict__ cursor, int* __restrict__ esrc_pad,
                              int e, int n) {
    int base = ((int)blockIdx.x * 256 + (int)threadIdx.x) * 8;
    int m = e - base; if (m > 8) m = 8;
    if (m <= 0) return;
    int dd[8], sv[8], pos[8];
#pragma unroll
    for (int k = 0; k < 8; k++)
        if (k < m) {
            int d = dst[base + k];
            dd[k] = (d < 0) ? 0 : ((d >= n) ? n - 1 : d);
            int s = src[base + k];
            sv[k] = (s < 0) ? 0 : ((s >= n) ? n - 1 : s);
        }
#pragma unroll
    for (int k = 0; k < 8; k++)
        if (k < m) pos[k] = atomicAdd(&cursor[dd[k]], 1);
#pragma unroll
    for (int k = 0; k < 8; k++)
        if (k < m && pos[k] < 64) esrc_pad[(dd[k] << 6) + pos[k]] = sv[k];
}

// ---------------- deg + weights transpose + xsc conversion, one launch ------------

__global__ void prep_k(const int* __restrict__ cnt, float* __restrict__ isd,
                       float* __restrict__ sdeg, int n, int gN,
                       const float* __restrict__ s0, const float* __restrict__ s1,
                       const float* __restrict__ s2, const float* __restrict__ s3,
                       const float* __restrict__ s4, const float* __restrict__ s5,
                       unsigned short* __restrict__ d0, unsigned short* __restrict__ d1,
                       unsigned short* __restrict__ d2, unsigned short* __restrict__ d3,
                       unsigned short* __restrict__ d4, unsigned short* __restrict__ d5,
                       const float* __restrict__ x, unsigned short* __restrict__ xsc,
                       int n4) {
    int b = blockIdx.x;
    if (b < gN) {
        int i = b * 256 + threadIdx.x;
        if (i < n) {
            float d = (float)cnt[i] + 1.0f;   // +1 self loop
            float r = rsqrtf(d);
            isd[i] = r;
            sdeg[i] = d * r;
        }
        return;
    }
    int b2 = b - gN;
    if (b2 < 1536) {
        int y = b2 >> 8, k = b2 & 255, nn = threadIdx.x;
        const float* S;
        unsigned short* D;
        int K;
        switch (y) {
            case 0: S = s0; D = d0; K = 128; break;
            case 1: S = s1; D = d1; K = 128; break;
            case 2: S = s2; D = d2; K = 256; break;
            case 3: S = s3; D = d3; K = 256; break;
            case 4: S = s4; D = d4; K = 256; break;
            default: S = s5; D = d5; K = 256; break;
        }
        if (k >= K) return;
        D[(size_t)nn * K + k] = f2bf(S[(size_t)k * 256 + nn]);
    } else {
        int i4 = (b2 - 1536) * 256 + threadIdx.x;
        if (i4 < n4) {
            float si = rsqrtf((float)cnt[i4 >> 5] + 1.0f);
            float4 v = ((const float4*)x)[i4];
            ushort4 o;
            o.x = f2bf(si * v.x); o.y = f2bf(si * v.y);
            o.z = f2bf(si * v.z); o.w = f2bf(si * v.w);
            ((ushort4*)xsc)[i4] = o;
        }
    }
}

// ---------------- bf16 MFMA GEMM: full-width 512-thread blocks, B in VGPRs ------------
// (unchanged — see prior rounds for flag semantics)

template <int K, bool BIAS, bool GELU_, bool SPRE, bool SCALE, bool STATS, bool HEAD,
          bool PF, bool FUSEA, bool WRITEH, bool BNIN>
__global__ __launch_bounds__(512) void gemm_bf_k(const unsigned short* __restrict__ A,
                                                 const unsigned short* __restrict__ Wt,
                                                 const float* __restrict__ bias,
                                                 const float* __restrict__ rowscale,
                                                 unsigned short* __restrict__ CB,
                                                 int M,
                                                 const float* __restrict__ hw,
                                                 const float* __restrict__ hb,
                                                 float* __restrict__ hout,
                                                 float* __restrict__ bnp_out,
                                                 const unsigned short* __restrict__ resid,
                                                 unsigned short* __restrict__ hwr,
                                                 const float* __restrict__ bnp_in,
                                                 const float* __restrict__ bn_g,
                                                 const float* __restrict__ bn_b,
                                                 float inv_n) {
    constexpr int CH = K / 32;
    const int lane = threadIdx.x & 63;
    const int wave = threadIdx.x >> 6;
    const int wm = wave & 1;               // row group (16 rows)
    const int wn = wave >> 1;              // col quarter
    const int l15 = lane & 15;
    const int quad = lane >> 4;

    __shared__ unsigned short al[FUSEA ? 2 * 32 * 256 : 1];
    __shared__ float hsum4[HEAD ? 128 : 1];
    __shared__ float st[STATS ? 1024 : 1];
    __shared__ float ssl[(FUSEA || BNIN) ? 512 : 1];   // [0..255]=scale, [256..511]=shift

    if constexpr (BNIN) {
        int t = threadIdx.x;
        if (t < 256) {
            float S = 0.f, S2 = 0.f;
#pragma unroll 8
            for (int r = 0; r < 64; r++) {
                S += bnp_in[r * 512 + t];
                S2 += bnp_in[r * 512 + 256 + t];
            }
            float mu = S * inv_n;
            float var = S2 * inv_n - mu * mu;
            float sc = bn_g[t] * rsqrtf(var + EPSV);
            ssl[t] = sc;
            ssl[256 + t] = bn_b[t] - mu * sc;
        }
        __syncthreads();
    }

    bf16x8 bfr[CH][4];
#pragma unroll
    for (int c = 0; c < CH; c++)
#pragma unroll
        for (int j = 0; j < 4; j++) {
            int col = wn * 64 + j * 16 + l15;
            bfr[c][j] = *(const bf16x8*)&Wt[(size_t)col * K + c * 32 + quad * 8];
        }

    float hwv[16];
    if (HEAD) {
#pragma unroll
        for (int j = 0; j < 4; j++) {
            float4 w4 = *(const float4*)&hw[wn * 64 + j * 16 + quad * 4];
            hwv[j * 4 + 0] = w4.x; hwv[j * 4 + 1] = w4.y;
            hwv[j * 4 + 2] = w4.z; hwv[j * 4 + 3] = w4.w;
        }
    }
    float sacc[STATS ? 16 : 1], s2acc[STATS ? 16 : 1];
    if (STATS) {
#pragma unroll
        for (int k = 0; k < 16; k++) { sacc[k] = 0.f; s2acc[k] = 0.f; }
    }

    const int nTiles = (M + 31) >> 5;
    const int gstride = gridDim.x;

    // FUSEA thread mapping for the transform stage
    const int tr = threadIdx.x >> 4;            // local row 0..31
    const int tc = (threadIdx.x & 15) * 16;     // col base (16 cols/thread)
    const int sw = (tr & 7) << 3;               // LDS slot swizzle (ushort units)
    const int rr = wm * 16 + l15;               // fragment row
    const int rsw = (rr & 7) << 3;

    bf16x8 a[CH];
    uint4 g0, g1, r0, r1;
    if (FUSEA) {
        int rt0 = blockIdx.x;
        if (rt0 < nTiles) {
            int grow = rt0 * 32 + tr;
            int gc = (grow < M) ? grow : (M - 1);
            const unsigned short* gp = &A[(size_t)gc * 256 + tc];
            const unsigned short* rp = &resid[(size_t)gc * 256 + tc];
            g0 = *(const uint4*)gp; g1 = *(const uint4*)(gp + 8);
            r0 = *(const uint4*)rp; r1 = *(const uint4*)(rp + 8);
        }
    } else if (PF) {
        int rt0 = blockIdx.x;
        if (rt0 < nTiles) {
            int g = rt0 * 32 + wm * 16 + l15;
            int gc = (g < M) ? g : (M - 1);
            const unsigned short* ap = &A[(size_t)gc * K + quad * 8];
#pragma unroll
            for (int c = 0; c < CH; c++) a[c] = *(const bf16x8*)(ap + c * 32);
        }
    }

    int p = 0;
    for (int rt = blockIdx.x; rt < nTiles; rt += gstride) {
        int gr = rt * 32 + wm * 16 + l15;

        if constexpr (FUSEA) {
            // transform current raw tile -> bf16, LDS (+ optional h store)
            int grow = rt * 32 + tr;
            float4 sa = *(const float4*)&ssl[tc];
            float4 sb = *(const float4*)&ssl[tc + 4];
            float4 sc = *(const float4*)&ssl[tc + 8];
            float4 sd = *(const float4*)&ssl[tc + 12];
            float4 ha = *(const float4*)&ssl[256 + tc];
            float4 hbv = *(const float4*)&ssl[256 + tc + 4];
            float4 hc = *(const float4*)&ssl[256 + tc + 8];
            float4 hd = *(const float4*)&ssl[256 + tc + 12];
            float scv[16] = {sa.x, sa.y, sa.z, sa.w, sb.x, sb.y, sb.z, sb.w,
                             sc.x, sc.y, sc.z, sc.w, sd.x, sd.y, sd.z, sd.w};
            float shv[16] = {ha.x, ha.y, ha.z, ha.w, hbv.x, hbv.y, hbv.z, hbv.w,
                             hc.x, hc.y, hc.z, hc.w, hd.x, hd.y, hd.z, hd.w};
            unsigned short gbuf[16], rbuf[16];
            *(uint4*)&gbuf[0] = g0; *(uint4*)&gbuf[8] = g1;
            *(uint4*)&rbuf[0] = r0; *(uint4*)&rbuf[8] = r1;
            unsigned short hv[16];
#pragma unroll
            for (int k = 0; k < 16; k++) {
                float v = bf2f(gbuf[k]) * scv[k] + shv[k];
                hv[k] = f2bf(gelu_f(v) + bf2f(rbuf[k]));
            }
            *(uint4*)&al[p * 8192 + tr * 256 + (tc ^ sw)] = *(const uint4*)&hv[0];
            *(uint4*)&al[p * 8192 + tr * 256 + ((tc + 8) ^ sw)] = *(const uint4*)&hv[8];
            if (WRITEH && grow < M) {
                *(uint4*)&hwr[(size_t)grow * 256 + tc] = *(const uint4*)&hv[0];
                *(uint4*)&hwr[(size_t)grow * 256 + tc + 8] = *(const uint4*)&hv[8];
            }
            // prefetch next raw tile (lands during MFMA of this tile)
            int rtn = rt + gstride;
            if (rtn < nTiles) {
                int gn = rtn * 32 + tr;
                int gc2 = (gn < M) ? gn : (M - 1);
                const unsigned short* gp = &A[(size_t)gc2 * 256 + tc];
                const unsigned short* rp = &resid[(size_t)gc2 * 256 + tc];
                g0 = *(const uint4*)gp; g1 = *(const uint4*)(gp + 8);
                r0 = *(const uint4*)rp; r1 = *(const uint4*)(rp + 8);
            }
            __syncthreads();
#pragma unroll
            for (int c = 0; c < CH; c++)
                a[c] = *(const bf16x8*)&al[p * 8192 + rr * 256 + ((c * 32 + quad * 8) ^ rsw)];
        } else if constexpr (!PF) {
            int grc = (gr < M) ? gr : (M - 1);
            const unsigned short* ap = &A[(size_t)grc * K + quad * 8];
#pragma unroll
            for (int c = 0; c < CH; c++) a[c] = *(const bf16x8*)(ap + c * 32);
        }

        bf16x8 an[CH];
        if (PF && !FUSEA) {
            int rtn = rt + gstride;
            if (rtn < nTiles) {
                int gn = rtn * 32 + wm * 16 + l15;
                int gcn = (gn < M) ? gn : (M - 1);
                const unsigned short* apn = &A[(size_t)gcn * K + quad * 8];
#pragma unroll
                for (int c = 0; c < CH; c++) an[c] = *(const bf16x8*)(apn + c * 32);
            }
        }

        floatx4 acc[4];
#pragma unroll
        for (int j = 0; j < 4; j++) acc[j] = (floatx4){0.f, 0.f, 0.f, 0.f};
#pragma unroll
        for (int c = 0; c < CH; c++)
#pragma unroll
            for (int j = 0; j < 4; j++)
                acc[j] = __builtin_amdgcn_mfma_f32_16x16x32_bf16(bfr[c][j], a[c], acc[j], 0, 0, 0);

        float hpart = 0.f;
        if (gr < M) {
            float rs = (SPRE || SCALE) ? rowscale[gr] : 1.0f;
#pragma unroll
            for (int j = 0; j < 4; j++) {
                int gc0 = wn * 64 + j * 16 + quad * 4;       // 4 consecutive C-cols
                float4 bv;
                if (BIAS) bv = *(const float4*)&bias[gc0];
                float v0 = acc[j][0], v1 = acc[j][1], v2 = acc[j][2], v3 = acc[j][3];
                if (SPRE) { v0 *= rs; v1 *= rs; v2 *= rs; v3 *= rs; }
                if (BIAS) { v0 += bv.x; v1 += bv.y; v2 += bv.z; v3 += bv.w; }
                if (GELU_) { v0 = gelu_f(v0); v1 = gelu_f(v1); v2 = gelu_f(v2); v3 = gelu_f(v3); }
                if (SCALE) { v0 *= rs; v1 *= rs; v2 *= rs; v3 *= rs; }
                if (STATS) {
                    sacc[j * 4 + 0] += v0; s2acc[j * 4 + 0] += v0 * v0;
                    sacc[j * 4 + 1] += v1; s2acc[j * 4 + 1] += v1 * v1;
                    sacc[j * 4 + 2] += v2; s2acc[j * 4 + 2] += v2 * v2;
                    sacc[j * 4 + 3] += v3; s2acc[j * 4 + 3] += v3 * v3;
                }
                if (HEAD) {
                    hpart += v0 * hwv[j * 4 + 0] + v1 * hwv[j * 4 + 1]
                           + v2 * hwv[j * 4 + 2] + v3 * hwv[j * 4 + 3];
                } else {
                    ushort4 o;
                    o.x = f2bf(v0); o.y = f2bf(v1); o.z = f2bf(v2); o.w = f2bf(v3);
                    *(ushort4*)&CB[(size_t)gr * DH + gc0] = o;
                }
            }
        }
        if constexpr (HEAD) {
            hpart += __shfl_xor(hpart, 16, 64);
            hpart += __shfl_xor(hpart, 32, 64);
            if (quad == 0) hsum4[wn * 32 + wm * 16 + l15] = hpart;
            __syncthreads();
            if (threadIdx.x < 32) {
                int grow = rt * 32 + (int)threadIdx.x;
                if (grow < M)
                    hout[grow] = hsum4[threadIdx.x] + hsum4[32 + threadIdx.x] +
                                 hsum4[64 + threadIdx.x] + hsum4[96 + threadIdx.x] + hb[0];
            }
            __syncthreads();
        }

        if constexpr (FUSEA) {
            p ^= 1;
        } else if (PF) {
#pragma unroll
            for (int c = 0; c < CH; c++) a[c] = an[c];
        }
    }

    if (STATS) {
#pragma unroll
        for (int m = 1; m < 16; m <<= 1) {
#pragma unroll
            for (int k = 0; k < 16; k++) {
                sacc[k] += __shfl_xor(sacc[k], m, 64);
                s2acc[k] += __shfl_xor(s2acc[k], m, 64);
            }
        }
        if (l15 == 0) {
#pragma unroll
            for (int j = 0; j < 4; j++)
#pragma unroll
                for (int k = 0; k < 4; k++) {
                    int col = wn * 64 + j * 16 + quad * 4 + k;
                    st[wm * 512 + col] = sacc[j * 4 + k];
                    st[wm * 512 + 256 + col] = s2acc[j * 4 + k];
                }
        }
        __syncthreads();
        int t = threadIdx.x;
        atomicAdd(&bnp_out[(size_t)(blockIdx.x & 63) * 512 + t], st[t] + st[512 + t]);
    }
}

// ------------- merged: proj GEMM (blocks [0,nProjB)) + layer-0 aggregation ------------

__global__ __launch_bounds__(512, 4) void aggx_proj_k(
        const unsigned short* __restrict__ xsc,
        const int* __restrict__ esrc_pad,
        const int* __restrict__ cnt,
        const float* __restrict__ isd,
        unsigned short* __restrict__ axs,
        int n, int nProjB,
        const unsigned short* __restrict__ pjt,
        const float* __restrict__ pjb,
        const float* __restrict__ sdeg,
        unsigned short* __restrict__ pjo) {
    if ((int)blockIdx.x < nProjB) {
        const int lane = threadIdx.x & 63;
        const int wave = threadIdx.x >> 6;
        const int wm = wave & 1;
        const int wn = wave >> 1;
        const int l15 = lane & 15;
        const int quad = lane >> 4;
        bf16x8 bfr[4][4];
#pragma unroll
        for (int c = 0; c < 4; c++)
#pragma unroll
            for (int j = 0; j < 4; j++) {
                int col = wn * 64 + j * 16 + l15;
                bfr[c][j] = *(const bf16x8*)&pjt[(size_t)col * 128 + c * 32 + quad * 8];
            }
        const int nTiles = (n + 31) >> 5;
        for (int rt = blockIdx.x; rt < nTiles; rt += nProjB) {
            int gr = rt * 32 + wm * 16 + l15;
            int grc = (gr < n) ? gr : (n - 1);
            const unsigned short* ap = &xsc[(size_t)grc * 128 + quad * 8];
            bf16x8 a[4];
#pragma unroll
            for (int c = 0; c < 4; c++) a[c] = *(const bf16x8*)(ap + c * 32);
            floatx4 acc[4];
#pragma unroll
            for (int j = 0; j < 4; j++) acc[j] = (floatx4){0.f, 0.f, 0.f, 0.f};
#pragma unroll
            for (int c = 0; c < 4; c++)
#pragma unroll
                for (int j = 0; j < 4; j++)
                    acc[j] = __builtin_amdgcn_mfma_f32_16x16x32_bf16(bfr[c][j], a[c], acc[j], 0, 0, 0);
            if (gr < n) {
                float rs = sdeg[gr];
#pragma unroll
                for (int j = 0; j < 4; j++) {
                    int gc0 = wn * 64 + j * 16 + quad * 4;
                    float4 bv = *(const float4*)&pjb[gc0];
                    ushort4 o;
                    o.x = f2bf(acc[j][0] * rs + bv.x);
                    o.y = f2bf(acc[j][1] * rs + bv.y);
                    o.z = f2bf(acc[j][2] * rs + bv.z);
                    o.w = f2bf(acc[j][3] * rs + bv.w);
                    *(ushort4*)&pjo[(size_t)gr * DH + gc0] = o;
                }
            }
        }
        return;
    }
    // ---- layer-0 aggregation: 16 rows per 512-thread block, padded adjacency ----
    int b = blockIdx.x - nProjB;
    int half = threadIdx.x >> 5;      // 0..15
    int sub = threadIdx.x & 31;
    int i = b * 16 + half;
    if (i >= n) return;
    int len = cnt[i]; if (len > 64) len = 64;
    const int* row = &esrc_pad[i << 6];
    int c = sub * 4;
    float acc[4] = {0.f, 0.f, 0.f, 0.f};
    addbf4(acc, *(const ushort4*)&xsc[(size_t)i * 128 + c]);   // self
    int e = 0;
    for (; e + 7 < len; e += 8) {
        int s[8];
        ushort4 u[8];
#pragma unroll
        for (int k = 0; k < 8; k++) s[k] = row[e + k];
#pragma unroll
        for (int k = 0; k < 8; k++) u[k] = *(const ushort4*)&xsc[(size_t)s[k] * 128 + c];
#pragma unroll
        for (int k = 0; k < 8; k++) addbf4(acc, u[k]);
    }
    for (; e + 1 < len; e += 2) {
        int s0 = row[e], s1 = row[e + 1];
        ushort4 a = *(const ushort4*)&xsc[(size_t)s0 * 128 + c];
        ushort4 bb = *(const ushort4*)&xsc[(size_t)s1 * 128 + c];
        addbf4(acc, a);
        addbf4(acc, bb);
    }
    if (e < len)
        addbf4(acc, *(const ushort4*)&xsc[(size_t)row[e] * 128 + c]);
    float si = isd[i];
    ushort4 o;
    o.x = f2bf(si * acc[0]); o.y = f2bf(si * acc[1]);
    o.z = f2bf(si * acc[2]); o.w = f2bf(si * acc[3]);
    *(ushort4*)&axs[(size_t)i * 128 + c] = o;
}

// ---------------- layers 1,2 aggregation + BN partial accumulate (r10-verified) ------
// 8-deep batched gathers, 8 rows/block; LDS reduce then atomic accumulate into
// bnp[64][512]. r11 post-mortem: XCD column-slicing raised FETCH 185->221GB and dur
// 64->180us (blockIdx->XCD locality assumption falsified) — this layout is the
// empirically best of {8-deep, 16-deep, col-sliced}.

__global__ __launch_bounds__(256) void agg_h_k(const unsigned short* __restrict__ hws,
                                               const int* __restrict__ esrc_pad,
                                               const int* __restrict__ cnt,
                                               const float* __restrict__ isd,
                                               const float* __restrict__ bias,
                                               unsigned short* __restrict__ out,
                                               float* __restrict__ bnp, int n) {
    __shared__ float ls[2048];
    int t = threadIdx.x;
    int half = t >> 5;
    int sub = t & 31;
    int c = sub * 8;
    int i = blockIdx.x * 8 + half;

    float o[8] = {0.f, 0.f, 0.f, 0.f, 0.f, 0.f, 0.f, 0.f};
    if (i < n) {
        int len = cnt[i]; if (len > 64) len = 64;
        const int* row = &esrc_pad[i << 6];
        float acc[8] = {0.f, 0.f, 0.f, 0.f, 0.f, 0.f, 0.f, 0.f};
        addbf8(acc, *(const uint4*)&hws[(size_t)i * DH + c]);   // self
        int e = 0;
        for (; e + 7 < len; e += 8) {
            int s[8];
            uint4 u[8];
#pragma unroll
            for (int k = 0; k < 8; k++) s[k] = row[e + k];
#pragma unroll
            for (int k = 0; k < 8; k++) u[k] = *(const uint4*)&hws[(size_t)s[k] * DH + c];
#pragma unroll
            for (int k = 0; k < 8; k++) addbf8(acc, u[k]);
        }
        for (; e + 1 < len; e += 2) {
            int s0 = row[e], s1 = row[e + 1];
            uint4 a = *(const uint4*)&hws[(size_t)s0 * DH + c];
            uint4 b = *(const uint4*)&hws[(size_t)s1 * DH + c];
            addbf8(acc, a);
            addbf8(acc, b);
        }
        if (e < len)
            addbf8(acc, *(const uint4*)&hws[(size_t)row[e] * DH + c]);
        float si = isd[i];
        float4 b0 = *(const float4*)&bias[c];
        float4 b1 = *(const float4*)&bias[c + 4];
        o[0] = si * acc[0] + b0.x; o[1] = si * acc[1] + b0.y;
        o[2] = si * acc[2] + b0.z; o[3] = si * acc[3] + b0.w;
        o[4] = si * acc[4] + b1.x; o[5] = si * acc[5] + b1.y;
        o[6] = si * acc[6] + b1.z; o[7] = si * acc[7] + b1.w;
        unsigned short ob[8];
#pragma unroll
        for (int k = 0; k < 8; k++) ob[k] = f2bf(o[k]);
        *(uint4*)&out[(size_t)i * DH + c] = *(const uint4*)ob;
    }
    *(float4*)&ls[half * 256 + c]     = make_float4(o[0], o[1], o[2], o[3]);
    *(float4*)&ls[half * 256 + c + 4] = make_float4(o[4], o[5], o[6], o[7]);
    __syncthreads();
    float s = 0.f, s2 = 0.f;
#pragma unroll
    for (int h = 0; h < 8; h++) {
        float v = ls[h * 256 + t];
        s += v;
        s2 += v * v;
    }
    size_t row2 = (size_t)(blockIdx.x & 63) * 512;
    atomicAdd(&bnp[row2 + t], s);
    atomicAdd(&bnp[row2 + 256 + t], s2);
}

// ---------------- launch ----------------

extern "C" void kernel_launch(void* const* d_in, const int* in_sizes, int n_in,
                              void* d_out, int out_size, void* d_ws, size_t ws_size,
                              hipStream_t stream) {
    const float* x = (const float*)d_in[0];
    const int* eidx = (const int*)d_in[1];       // int64 in ref -> int32 on device
    const float* conv_w0 = (const float*)d_in[3];
    const float* conv_b0 = (const float*)d_in[4];
    const float* conv_w1 = (const float*)d_in[5];
    const float* conv_b1 = (const float*)d_in[6];
    const float* conv_w2 = (const float*)d_in[7];
    const float* conv_b2 = (const float*)d_in[8];
    const float* bn_g0 = (const float*)d_in[9];
    const float* bn_b0 = (const float*)d_in[10];
    const float* bn_g1 = (const float*)d_in[11];
    const float* bn_b1 = (const float*)d_in[12];
    const float* bn_g2 = (const float*)d_in[13];
    const float* bn_b2 = (const float*)d_in[14];
    const float* proj_w = (const float*)d_in[15];
    const float* proj_b = (const float*)d_in[16];
    const float* lin_w0 = (const float*)d_in[17];
    const float* lin_b0 = (const float*)d_in[18];
    const float* lin_w1 = (const float*)d_in[19];
    const float* lin_b1 = (const float*)d_in[20];
    const float* head_w = (const float*)d_in[21];
    const float* head_b = (const float*)d_in[22];

    const int N = in_sizes[2];
    const int E = in_sizes[1] / 2;
    const int* esrc_in = eidx;
    const int* edst_in = eidx + E;

    char* ws = (char*)d_ws;
    auto alloc = [&](size_t b) -> char* {
        char* p = ws;
        ws += (b + 255) & ~(size_t)255;
        return p;
    };
    unsigned short* h1_bf = (unsigned short*)alloc((size_t)N * DH * 2);
    unsigned short* h2_bf = (unsigned short*)alloc((size_t)N * DH * 2);
    unsigned short* hw_bf = (unsigned short*)alloc((size_t)N * DH * 2);
    unsigned short* pj_bf = (unsigned short*)alloc((size_t)N * DH * 2);
    unsigned short* gcn_bf = (unsigned short*)alloc((size_t)N * DH * 2);
    unsigned short* xsc = (unsigned short*)alloc((size_t)N * 128 * 2);
    unsigned short* axs = (unsigned short*)alloc((size_t)N * 128 * 2);
    unsigned short* w0t = (unsigned short*)alloc((size_t)256 * 128 * 2);
    unsigned short* pjt = (unsigned short*)alloc((size_t)256 * 128 * 2);
    unsigned short* w1t = (unsigned short*)alloc((size_t)256 * 256 * 2);
    unsigned short* w2t = (unsigned short*)alloc((size_t)256 * 256 * 2);
    unsigned short* l0t = (unsigned short*)alloc((size_t)256 * 256 * 2);
    unsigned short* l1t = (unsigned short*)alloc((size_t)256 * 256 * 2);
    // ---- zeroed region: 3 BN partial buffers + cursor (ONE memset) ----
    float* bnp0 = (float*)alloc((size_t)64 * 512 * 4);
    float* bnp1 = (float*)alloc((size_t)64 * 512 * 4);
    float* bnp2 = (float*)alloc((size_t)64 * 512 * 4);
    int* cursor = (int*)alloc((size_t)N * 4);       // slot counter -> degree
    const size_t zbytes = 3 * (size_t)64 * 512 * 4 + (size_t)N * 4;
    // ---- end zeroed region ----
    int* esrc_pad = (int*)alloc((size_t)N * 64 * 4);
    float* isd = (float*)alloc((size_t)N * 4);
    float* sdeg = (float*)alloc((size_t)N * 4);

    const int gE8 = (E + 2047) / 2048;           // 8 edges/thread scatter blocks
    const int gHalf = (N + 7) / 8;
    const int gAgg16 = (N + 15) / 16;
    const int gN = (N + 255) / 256;
    const int gGemm = 256;                       // persistent full-width blocks (1/CU)
    const int n4 = N * 128 / 4;
    const int gPrep = gN + 1536 + (n4 + 255) / 256;
    const float inv_n = 1.0f / (float)N;

    hipMemsetAsync(bnp0, 0, zbytes, stream);
    // count-free CSR: scatter directly into padded adjacency (atomic slot = degree)
    scatter_pad_k<<<gE8, 256, 0, stream>>>(esrc_in, edst_in, cursor, esrc_pad, E, N);
    // deg (from cursor) + weight transposes + xsc, one launch
    prep_k<<<gPrep, 256, 0, stream>>>(cursor, isd, sdeg, N, gN,
                                      conv_w0, proj_w, conv_w1, conv_w2, lin_w0, lin_w1,
                                      w0t, pjt, w1t, w2t, l0t, l1t, x, xsc, n4);

    // ---- layer 0: proj GEMM + aggregation merged ----
    aggx_proj_k<<<256 + gAgg16, 512, 0, stream>>>(xsc, esrc_pad, cursor, isd, axs, N,
                                                  256, pjt, proj_b, sdeg, pj_bf);
    // conv0 GEMM, BN stats -> bnp0 (atomic accumulate)
    gemm_bf_k<128, true, false, false, false, true, false, true, false, false, false>
        <<<gGemm, 512, 0, stream>>>(axs, w0t, conv_b0, nullptr, gcn_bf, N,
                                    nullptr, nullptr, nullptr, bnp0, nullptr, nullptr,
                                    nullptr, nullptr, nullptr, 0.f);

    // ---- layer 1: BNIN(bnp0) + fused BN+gelu+residual A-stage; agg -> bnp1 ----
    gemm_bf_k<256, false, false, false, true, false, false, false, true, true, true>
        <<<gGemm, 512, 0, stream>>>(gcn_bf, w1t, nullptr, isd, hw_bf, N,
                                    nullptr, nullptr, nullptr, nullptr, pj_bf, h1_bf,
                                    bnp0, bn_g0, bn_b0, inv_n);
    agg_h_k<<<gHalf, 256, 0, stream>>>(hw_bf, esrc_pad, cursor, isd, conv_b1, gcn_bf, bnp1, N);

    // ---- layer 2: BNIN(bnp1) + fused A-stage; agg -> bnp2 ----
    gemm_bf_k<256, false, false, false, true, false, false, false, true, true, true>
        <<<gGemm, 512, 0, stream>>>(gcn_bf, w2t, nullptr, isd, hw_bf, N,
                                    nullptr, nullptr, nullptr, nullptr, h1_bf, h2_bf,
                                    bnp1, bn_g1, bn_b1, inv_n);
    agg_h_k<<<gHalf, 256, 0, stream>>>(hw_bf, esrc_pad, cursor, isd, conv_b2, gcn_bf, bnp2, N);

    // ---- MLP: lin0 with BNIN(bnp2) + fused h3 A-stage (h3 not materialized) ----
    gemm_bf_k<256, true, true, false, false, false, false, false, true, false, true>
        <<<gGemm, 512, 0, stream>>>(gcn_bf, l0t, lin_b0, nullptr, h1_bf, N,
                                    nullptr, nullptr, nullptr, nullptr, h2_bf, nullptr,
                                    bnp2, bn_g2, bn_b2, inv_n);
    // lin1 + head fused (LDS combine, non-atomic store -> no d_out memset)
    gemm_bf_k<256, true, true, false, false, false, true, false, false, false, false>
        <<<gGemm, 512, 0, stream>>>(h1_bf, l1t, lin_b1, nullptr, nullptr, N,
                                    head_w, head_b, (float*)d_out, nullptr, nullptr, nullptr,
                                    nullptr, nullptr, nullptr, 0.f);
}